// Round 1
// baseline (70.494 us; speedup 1.0000x reference)
//
#include <hip/hip_runtime.h>
#include <stdint.h>

// IntraModalLoss: loss = 0.5*mean_i softplus(T - ||z_i||^2) + 0.5*mean_{i!=j} softplus(z_i.z_j - T)
// z = row-normalized emb.  sim computed as bf16 MFMA (symmetric: only bc>=br tiles, x2 weight).

#define TEMP 0.2f
#define NROW 8192
#define DIM  256
#define NT   64     // 8192/128 tiles per dim
#define BM   128

typedef __attribute__((ext_vector_type(8))) __bf16 bf16x8;
typedef __attribute__((ext_vector_type(4))) float  f32x4;

__device__ __forceinline__ unsigned short f2bf(float f) {
    unsigned int u = __float_as_uint(f);
    u += 0x7FFFu + ((u >> 16) & 1u);          // round-to-nearest-even
    return (unsigned short)(u >> 16);
}

__device__ __forceinline__ float softplus_f(float x) {
    return __logf(1.0f + __expf(x));          // x in [-1.2, 0.8]: no overflow/cancellation
}

// ---- K1: row-normalize, emit bf16 z, per-row positives term -------------------
__global__ __launch_bounds__(256) void k_normalize(const float* __restrict__ emb,
                                                   unsigned short* __restrict__ zb,
                                                   float* __restrict__ pos) {
    const int gw   = (int)((blockIdx.x * blockDim.x + threadIdx.x) >> 6); // one wave per row
    const int lane = threadIdx.x & 63;
    if (gw >= NROW) return;
    const float4* rp = (const float4*)(emb + (size_t)gw * DIM);
    float4 v = rp[lane];
    float ss = v.x * v.x + v.y * v.y + v.z * v.z + v.w * v.w;
#pragma unroll
    for (int off = 32; off >= 1; off >>= 1) ss += __shfl_xor(ss, off);
    float nrm = sqrtf(ss);
    float inv = 1.0f / fmaxf(nrm, 1e-12f);
    ushort4 o;
    o.x = f2bf(v.x * inv);
    o.y = f2bf(v.y * inv);
    o.z = f2bf(v.z * inv);
    o.w = f2bf(v.w * inv);
    ((ushort4*)(zb + (size_t)gw * DIM))[lane] = o;
    if (lane == 0) {
        float sii = ss * inv * inv;           // diag(sim) in fp32, ~1.0
        pos[gw] = softplus_f(TEMP - sii);
    }
}

// ---- K2: fused 128x128 sim tile (bf16 MFMA) + softplus + block partial --------
// LDS panels [128 rows][256B] per operand, XOR-swizzled: byte ^= ((row&7)<<4).
// Staged with global_load_lds (linear dest) + inverse-swizzled global source.
__global__ __launch_bounds__(256, 2) void k_simloss(const unsigned short* __restrict__ zb,
                                                    float* __restrict__ negp) {
    const int br = blockIdx.y, bc = blockIdx.x;
    const int bid = br * NT + bc;
    if (bc < br) {                            // symmetric: skip lower triangle
        if (threadIdx.x == 0) negp[bid] = 0.0f;
        return;
    }
    __shared__ __align__(128) unsigned char lds[65536];  // A: [0,32K)  B: [32K,64K)
    __shared__ float red[4];

    const int t    = threadIdx.x;
    const int lane = t & 63;
    const int w    = t >> 6;                  // 4 waves, 2x2 -> 64x64 each
    const int wr   = w >> 1, wc = w & 1;

    const f32x4 zero4 = {0.f, 0.f, 0.f, 0.f};
    f32x4 acc[4][4];
#pragma unroll
    for (int m = 0; m < 4; ++m)
#pragma unroll
        for (int n = 0; n < 4; ++n) acc[m][n] = zero4;

    const char* zB = (const char*)zb;
    const size_t rowA0 = (size_t)br * BM;
    const size_t rowB0 = (size_t)bc * BM;

    for (int kt = 0; kt < 2; ++kt) {          // K = 256 in two 128-wide steps
        __syncthreads();                      // protect LDS from previous compute
#pragma unroll
        for (int it = 0; it < 8; ++it) {
            int d    = it * 4096 + w * 1024 + lane * 16;   // linear LDS dest
            int row  = d >> 8;                              // 256B per row
            int colb = (d & 255) ^ ((row & 7) << 4);        // inverse swizzle on source
            const char* gA = zB + (rowA0 + row) * (DIM * 2) + kt * 256 + colb;
            const char* gB = zB + (rowB0 + row) * (DIM * 2) + kt * 256 + colb;
            __builtin_amdgcn_global_load_lds((const unsigned int*)gA,
                                             (unsigned int*)(lds + d), 16, 0, 0);
            __builtin_amdgcn_global_load_lds((const unsigned int*)gB,
                                             (unsigned int*)(lds + 32768 + d), 16, 0, 0);
        }
        __syncthreads();

#pragma unroll
        for (int ks = 0; ks < 4; ++ks) {      // 4 k-steps of 32
            bf16x8 af[4], bfr[4];
            const int kb = ks * 64 + (lane >> 4) * 16;     // byte offset of lane's 8 k-elems
#pragma unroll
            for (int m = 0; m < 4; ++m) {
                int row = wr * 64 + m * 16 + (lane & 15);
                af[m] = *(const bf16x8*)(lds + row * 256 + (kb ^ ((row & 7) << 4)));
            }
#pragma unroll
            for (int n = 0; n < 4; ++n) {
                int row = wc * 64 + n * 16 + (lane & 15);
                bfr[n] = *(const bf16x8*)(lds + 32768 + row * 256 + (kb ^ ((row & 7) << 4)));
            }
#pragma unroll
            for (int m = 0; m < 4; ++m)
#pragma unroll
                for (int n = 0; n < 4; ++n)
                    acc[m][n] = __builtin_amdgcn_mfma_f32_16x16x32_bf16(af[m], bfr[n],
                                                                        acc[m][n], 0, 0, 0);
        }
    }

    // epilogue: softplus(sim - T) over off-diagonal, block partial sum
    float local = 0.0f;
    const int gi0 = br * BM + wr * 64 + ((lane >> 4) << 2);  // C/D: row=(lane>>4)*4+q
    const int gj0 = bc * BM + wc * 64 + (lane & 15);         //      col=lane&15
#pragma unroll
    for (int m = 0; m < 4; ++m)
#pragma unroll
        for (int n = 0; n < 4; ++n)
#pragma unroll
            for (int q = 0; q < 4; ++q) {
                float s = acc[m][n][q];
                int gi = gi0 + m * 16 + q;
                int gj = gj0 + n * 16;
                float sp = softplus_f(s - TEMP);
                local += (gi == gj) ? 0.0f : sp;
            }
#pragma unroll
    for (int off = 32; off >= 1; off >>= 1) local += __shfl_xor(local, off);
    if (lane == 0) red[w] = local;
    __syncthreads();
    if (t == 0) {
        float tot = red[0] + red[1] + red[2] + red[3];
        if (br != bc) tot *= 2.0f;            // off-diagonal tiles count twice
        negp[bid] = tot;
    }
}

// ---- K3: deterministic final reduce ------------------------------------------
__global__ __launch_bounds__(256) void k_reduce(const float* __restrict__ pos,
                                                const float* __restrict__ negp,
                                                float* __restrict__ out) {
    __shared__ float sp[256], sn[256];
    const int t = threadIdx.x;
    float ps = 0.f, ns = 0.f;
    for (int i = t; i < NROW; i += 256) ps += pos[i];
    for (int i = t; i < NT * NT; i += 256) ns += negp[i];
    sp[t] = ps; sn[t] = ns;
    __syncthreads();
    for (int s = 128; s >= 1; s >>= 1) {
        if (t < s) { sp[t] += sp[t + s]; sn[t] += sn[t + s]; }
        __syncthreads();
    }
    if (t == 0) {
        double positives_sum = (double)sp[0] / (double)NROW;
        double negatives_sum = (double)sn[0] / ((double)NROW * (double)(NROW - 1));
        out[0] = (float)(0.5 * positives_sum + 0.5 * negatives_sum);
    }
}

extern "C" void kernel_launch(void* const* d_in, const int* in_sizes, int n_in,
                              void* d_out, int out_size, void* d_ws, size_t ws_size,
                              hipStream_t stream) {
    const float* emb = (const float*)d_in[0];
    float* out = (float*)d_out;

    unsigned short* zb  = (unsigned short*)d_ws;                       // 4 MB bf16 z
    float* pos  = (float*)((char*)d_ws + (size_t)NROW * DIM * 2);      // 32 KB
    float* negp = pos + NROW;                                          // 16 KB

    k_normalize<<<NROW / 4, 256, 0, stream>>>(emb, zb, pos);
    k_simloss<<<dim3(NT, NT), 256, 0, stream>>>(zb, negp);
    k_reduce<<<1, 256, 0, stream>>>(pos, negp, out);
}